// Round 1
// baseline (1226.912 us; speedup 1.0000x reference)
//
#include <hip/hip_runtime.h>
#include <hip/hip_bf16.h>

#define N_NODES 100000
#define N_EDGES 1600000
#define IN_DIM 128
#define HID 64
#define N_GRAPHS 64
#define OUT_DIM 2

#define SCAN_BLOCK 1024
#define SCAN_NB ((N_NODES + SCAN_BLOCK - 1) / SCAN_BLOCK)

// ---------------- edge preprocessing ----------------

__global__ void k_hist(const int* __restrict__ dst, int* __restrict__ deg) {
    int e = blockIdx.x * blockDim.x + threadIdx.x;
    if (e < N_EDGES) atomicAdd(&deg[dst[e]], 1);
}

__global__ void k_dis(const int* __restrict__ deg, float* __restrict__ dis) {
    int i = blockIdx.x * blockDim.x + threadIdx.x;
    if (i < N_NODES) dis[i] = rsqrtf((float)deg[i] + 1.0f);  // +1 = self-loop
}

__global__ void k_scan1(const int* __restrict__ deg, int* __restrict__ off,
                        int* __restrict__ bsums) {
    __shared__ int s[SCAN_BLOCK];
    int t = threadIdx.x;
    int i = blockIdx.x * SCAN_BLOCK + t;
    int v = (i < N_NODES) ? deg[i] : 0;
    s[t] = v;
    __syncthreads();
    for (int d = 1; d < SCAN_BLOCK; d <<= 1) {
        int add = (t >= d) ? s[t - d] : 0;
        __syncthreads();
        s[t] += add;
        __syncthreads();
    }
    if (i < N_NODES) off[i + 1] = s[t];
    if (t == SCAN_BLOCK - 1) bsums[blockIdx.x] = s[t];
}

__global__ void k_scan2(int* __restrict__ bsums, int* __restrict__ off) {
    if (blockIdx.x == 0 && threadIdx.x == 0) {
        int acc = 0;
        for (int b = 0; b < SCAN_NB; ++b) {
            int v = bsums[b];
            bsums[b] = acc;
            acc += v;
        }
        off[0] = 0;
    }
}

__global__ void k_scan3(int* __restrict__ off, const int* __restrict__ bsums) {
    int i = blockIdx.x * SCAN_BLOCK + threadIdx.x;
    if (i < N_NODES) off[i + 1] += bsums[blockIdx.x];
}

__global__ void k_copy(const int* __restrict__ off, int* __restrict__ cursor) {
    int i = blockIdx.x * blockDim.x + threadIdx.x;
    if (i < N_NODES) cursor[i] = off[i];
}

__global__ void k_scatter(const int* __restrict__ src, const int* __restrict__ dst,
                          int* __restrict__ cursor, int* __restrict__ ssrc) {
    int e = blockIdx.x * blockDim.x + threadIdx.x;
    if (e < N_EDGES) {
        int p = atomicAdd(&cursor[dst[e]], 1);
        ssrc[p] = src[e];
    }
}

// ---------------- conv = scaled GEMM + gather-aggregate ----------------

// g[i,f] = dis[i] * sum_k h[i,k] * W[k,f]
template <int K>
__global__ void k_gemm(const float* __restrict__ h, const float* __restrict__ W,
                       const float* __restrict__ dis, float* __restrict__ g) {
    int row = blockIdx.x * 4 + (threadIdx.x >> 6);
    int lane = threadIdx.x & 63;
    if (row >= N_NODES) return;
    const float* hr = h + (size_t)row * K;
    float acc = 0.f;
#pragma unroll 8
    for (int k = 0; k < K; ++k) acc = fmaf(hr[k], W[k * HID + lane], acc);
    g[(size_t)row * HID + lane] = acc * dis[row];
}

// hout[i,f] = act( dis[i] * (g[i,f] + sum_{e in [off[i],off[i+1])} g[ssrc[e], f]) + b[f] )
template <bool RELU>
__global__ void k_aggr(const float* __restrict__ g, const int* __restrict__ off,
                       const int* __restrict__ ssrc, const float* __restrict__ dis,
                       const float* __restrict__ bias, float* __restrict__ hout) {
    int row = blockIdx.x * 4 + (threadIdx.x >> 6);
    int lane = threadIdx.x & 63;
    if (row >= N_NODES) return;
    float acc = g[(size_t)row * HID + lane];  // self-loop term (pre-scaled by dis[row])
    int lo = off[row], hi = off[row + 1];
    for (int e = lo; e < hi; ++e) {
        int s = ssrc[e];
        acc += g[(size_t)s * HID + lane];
    }
    float v = dis[row] * acc + bias[lane];
    if (RELU) v = fmaxf(v, 0.f);
    hout[(size_t)row * HID + lane] = v;
}

// ---------------- pooling + classifier ----------------

__device__ inline int lower_bound_batch(const int* batch, int key) {
    int lo = 0, hi = N_NODES;
    while (lo < hi) {
        int mid = (lo + hi) >> 1;
        if (batch[mid] < key) lo = mid + 1;
        else hi = mid;
    }
    return lo;
}

__global__ void k_pool(const float* __restrict__ h, const int* __restrict__ batch,
                       float* __restrict__ pooled) {
    int gidx = blockIdx.x;  // one block per graph
    int lane = threadIdx.x & 63, w = threadIdx.x >> 6;
    __shared__ float sacc[4][HID];
    int lo = lower_bound_batch(batch, gidx);
    int hi = lower_bound_batch(batch, gidx + 1);
    float acc = 0.f;
    for (int i = lo + w; i < hi; i += 4) acc += h[(size_t)i * HID + lane];
    sacc[w][lane] = acc;
    __syncthreads();
    if (w == 0) {
        float s = sacc[0][lane] + sacc[1][lane] + sacc[2][lane] + sacc[3][lane];
        float cnt = (float)(hi - lo);
        pooled[gidx * HID + lane] = s / fmaxf(cnt, 1.0f);
    }
}

__global__ void k_cls(const float* __restrict__ pooled, const float* __restrict__ Wc1,
                      const float* __restrict__ bc1, const float* __restrict__ Wc2,
                      const float* __restrict__ bc2, float* __restrict__ out) {
    __shared__ float hc[N_GRAPHS][HID / 2];
    int t = threadIdx.x;
    for (int idx = t; idx < N_GRAPHS * (HID / 2); idx += blockDim.x) {
        int gi = idx >> 5, f = idx & 31;
        float a = bc1[f];
#pragma unroll
        for (int k = 0; k < HID; ++k) a = fmaf(pooled[gi * HID + k], Wc1[k * (HID / 2) + f], a);
        hc[gi][f] = fmaxf(a, 0.f);
    }
    __syncthreads();
    for (int idx = t; idx < N_GRAPHS * OUT_DIM; idx += blockDim.x) {
        int gi = idx >> 1, f = idx & 1;
        float a = bc2[f];
#pragma unroll
        for (int k = 0; k < HID / 2; ++k) a = fmaf(hc[gi][k], Wc2[k * OUT_DIM + f], a);
        out[gi * OUT_DIM + f] = a;
    }
}

// ---------------- launch ----------------

extern "C" void kernel_launch(void* const* d_in, const int* in_sizes, int n_in,
                              void* d_out, int out_size, void* d_ws, size_t ws_size,
                              hipStream_t stream) {
    const float* x    = (const float*)d_in[0];
    const int*   eidx = (const int*)d_in[1];   // [2, E] flat: src row then dst row
    const int*   batch= (const int*)d_in[2];
    const float* W1 = (const float*)d_in[3];  const float* b1 = (const float*)d_in[4];
    const float* W2 = (const float*)d_in[5];  const float* b2 = (const float*)d_in[6];
    const float* W3 = (const float*)d_in[7];  const float* b3 = (const float*)d_in[8];
    const float* Wc1 = (const float*)d_in[9];  const float* bc1 = (const float*)d_in[10];
    const float* Wc2 = (const float*)d_in[11]; const float* bc2 = (const float*)d_in[12];
    float* out = (float*)d_out;

    const int* esrc = eidx;
    const int* edst = eidx + N_EDGES;

    // workspace layout (256B aligned)
    size_t o = 0;
    auto alloc = [&](size_t bytes) {
        void* p = (char*)d_ws + o;
        o += (bytes + 255) & ~(size_t)255;
        return p;
    };
    int*   deg_cur = (int*)alloc((size_t)N_NODES * 4);        // deg, later cursor
    int*   off     = (int*)alloc((size_t)(N_NODES + 1) * 4);
    int*   bsums   = (int*)alloc((size_t)SCAN_NB * 4);
    float* dis     = (float*)alloc((size_t)N_NODES * 4);
    int*   ssrc    = (int*)alloc((size_t)N_EDGES * 4);
    float* g       = (float*)alloc((size_t)N_NODES * HID * 4);
    float* hbuf    = (float*)alloc((size_t)N_NODES * HID * 4);
    float* pooled  = (float*)alloc((size_t)N_GRAPHS * HID * 4);
    (void)ws_size;

    const int TB = 256;
    int gridN  = (N_NODES + TB - 1) / TB;
    int gridE  = (N_EDGES + TB - 1) / TB;
    int gridR  = (N_NODES + 3) / 4;  // 4 rows (waves) per 256-thread block

    // 1) degree histogram + dis
    hipMemsetAsync(deg_cur, 0, (size_t)N_NODES * 4, stream);
    k_hist<<<gridE, TB, 0, stream>>>(edst, deg_cur);
    k_dis<<<gridN, TB, 0, stream>>>(deg_cur, dis);

    // 2) exclusive scan deg -> off, cursor = off
    k_scan1<<<SCAN_NB, SCAN_BLOCK, 0, stream>>>(deg_cur, off, bsums);
    k_scan2<<<1, 64, 0, stream>>>(bsums, off);
    k_scan3<<<SCAN_NB, SCAN_BLOCK, 0, stream>>>(off, bsums);
    k_copy<<<gridN, TB, 0, stream>>>(off, deg_cur);  // deg_cur now = cursor

    // 3) counting-sort edges by dst
    k_scatter<<<gridE, TB, 0, stream>>>(esrc, edst, deg_cur, ssrc);

    // 4) conv1: x[100000,128] -> h
    k_gemm<IN_DIM><<<gridR, TB, 0, stream>>>(x, W1, dis, g);
    k_aggr<true><<<gridR, TB, 0, stream>>>(g, off, ssrc, dis, b1, hbuf);

    // 5) conv2
    k_gemm<HID><<<gridR, TB, 0, stream>>>(hbuf, W2, dis, g);
    k_aggr<true><<<gridR, TB, 0, stream>>>(g, off, ssrc, dis, b2, hbuf);

    // 6) conv3 (no relu)
    k_gemm<HID><<<gridR, TB, 0, stream>>>(hbuf, W3, dis, g);
    k_aggr<false><<<gridR, TB, 0, stream>>>(g, off, ssrc, dis, b3, hbuf);

    // 7) pool + classifier
    k_pool<<<N_GRAPHS, TB, 0, stream>>>(hbuf, batch, pooled);
    k_cls<<<1, TB, 0, stream>>>(pooled, Wc1, bc1, Wc2, bc2, out);
}

// Round 2
// 674.537 us; speedup vs baseline: 1.8189x; 1.8189x over previous
//
#include <hip/hip_runtime.h>
#include <hip/hip_bf16.h>

#define N_NODES 100000
#define N_EDGES 1600000
#define IN_DIM 128
#define HID 64
#define N_GRAPHS 64
#define OUT_DIM 2

#define SCAN_BLOCK 1024
#define SCAN_NB ((N_NODES + SCAN_BLOCK - 1) / SCAN_BLOCK)

// ---------------- edge preprocessing ----------------

__global__ void k_hist(const int* __restrict__ dst, int* __restrict__ deg) {
    int e = blockIdx.x * blockDim.x + threadIdx.x;
    if (e < N_EDGES) atomicAdd(&deg[dst[e]], 1);
}

__global__ void k_dis(const int* __restrict__ deg, float* __restrict__ dis) {
    int i = blockIdx.x * blockDim.x + threadIdx.x;
    if (i < N_NODES) dis[i] = rsqrtf((float)deg[i] + 1.0f);  // +1 = self-loop
}

__global__ void k_scan1(const int* __restrict__ deg, int* __restrict__ off,
                        int* __restrict__ bsums) {
    __shared__ int s[SCAN_BLOCK];
    int t = threadIdx.x;
    int i = blockIdx.x * SCAN_BLOCK + t;
    int v = (i < N_NODES) ? deg[i] : 0;
    s[t] = v;
    __syncthreads();
    for (int d = 1; d < SCAN_BLOCK; d <<= 1) {
        int add = (t >= d) ? s[t - d] : 0;
        __syncthreads();
        s[t] += add;
        __syncthreads();
    }
    if (i < N_NODES) off[i + 1] = s[t];
    if (t == SCAN_BLOCK - 1) bsums[blockIdx.x] = s[t];
}

__global__ void k_scan2(int* __restrict__ bsums, int* __restrict__ off,
                        int* __restrict__ cursor) {
    if (blockIdx.x == 0 && threadIdx.x == 0) {
        int acc = 0;
        for (int b = 0; b < SCAN_NB; ++b) {
            int v = bsums[b];
            bsums[b] = acc;
            acc += v;
        }
        off[0] = 0;
        cursor[0] = 0;
    }
}

// writes final off[i+1] AND cursor[i+1] (cursor = copy of off for the scatter)
__global__ void k_scan3(int* __restrict__ off, const int* __restrict__ bsums,
                        int* __restrict__ cursor) {
    int i = blockIdx.x * SCAN_BLOCK + threadIdx.x;
    if (i < N_NODES) {
        int v = off[i + 1] + bsums[blockIdx.x];
        off[i + 1] = v;
        cursor[i + 1] = v;
    }
}

__global__ void k_scatter(const int* __restrict__ src, const int* __restrict__ dst,
                          int* __restrict__ cursor, int* __restrict__ ssrc) {
    int e = blockIdx.x * blockDim.x + threadIdx.x;
    if (e < N_EDGES) {
        int p = atomicAdd(&cursor[dst[e]], 1);
        ssrc[p] = src[e];
    }
}

// ---------------- conv = scaled GEMM + gather-aggregate ----------------

// g[i,f] = dis[i] * sum_k A[i,k] * W[k,f]
// LDS-tiled f32 GEMM: 64 rows x 64 cols per 256-thread block, BK=32.
// Each thread owns a 4x4 register tile; per k: 2x ds_read_b128 + 16 FMA.
template <int K>
__global__ __launch_bounds__(256) void k_gemm(const float* __restrict__ A,
                                              const float* __restrict__ W,
                                              const float* __restrict__ dis,
                                              float* __restrict__ g) {
    __shared__ float As[32][68];  // [kk][row], pad 64->68 keeps 16B alignment, no conflicts
    __shared__ float Ws[32][64];  // [kk][col]
    int t = threadIdx.x;
    int tx = t & 15, ty = t >> 4;
    int row0 = blockIdx.x * 64;
    float acc[4][4] = {{0.f}};

    int ar = t >> 3;          // 0..31; handles rows ar and ar+32
    int ak = (t & 7) * 4;     // k offset within chunk

    for (int k0 = 0; k0 < K; k0 += 32) {
#pragma unroll
        for (int half = 0; half < 2; ++half) {
            int r = ar + half * 32;
            int grow = row0 + r;
            grow = grow < N_NODES ? grow : N_NODES - 1;  // clamp (garbage rows unstored)
            float4 v = *(const float4*)&A[(size_t)grow * K + k0 + ak];
            As[ak + 0][r] = v.x;
            As[ak + 1][r] = v.y;
            As[ak + 2][r] = v.z;
            As[ak + 3][r] = v.w;
        }
#pragma unroll
        for (int h = 0; h < 2; ++h) {
            int i4 = t + h * 256;          // float4 index into 32x64 chunk
            int kk = i4 >> 4;
            int c4 = (i4 & 15) * 4;
            *(float4*)&Ws[kk][c4] = *(const float4*)&W[(size_t)(k0 + kk) * HID + c4];
        }
        __syncthreads();
#pragma unroll
        for (int kk = 0; kk < 32; ++kk) {
            float4 a = *(const float4*)&As[kk][ty * 4];
            float4 b = *(const float4*)&Ws[kk][tx * 4];
            acc[0][0] = fmaf(a.x, b.x, acc[0][0]);
            acc[0][1] = fmaf(a.x, b.y, acc[0][1]);
            acc[0][2] = fmaf(a.x, b.z, acc[0][2]);
            acc[0][3] = fmaf(a.x, b.w, acc[0][3]);
            acc[1][0] = fmaf(a.y, b.x, acc[1][0]);
            acc[1][1] = fmaf(a.y, b.y, acc[1][1]);
            acc[1][2] = fmaf(a.y, b.z, acc[1][2]);
            acc[1][3] = fmaf(a.y, b.w, acc[1][3]);
            acc[2][0] = fmaf(a.z, b.x, acc[2][0]);
            acc[2][1] = fmaf(a.z, b.y, acc[2][1]);
            acc[2][2] = fmaf(a.z, b.z, acc[2][2]);
            acc[2][3] = fmaf(a.z, b.w, acc[2][3]);
            acc[3][0] = fmaf(a.w, b.x, acc[3][0]);
            acc[3][1] = fmaf(a.w, b.y, acc[3][1]);
            acc[3][2] = fmaf(a.w, b.z, acc[3][2]);
            acc[3][3] = fmaf(a.w, b.w, acc[3][3]);
        }
        __syncthreads();
    }

#pragma unroll
    for (int j = 0; j < 4; ++j) {
        int grow = row0 + ty * 4 + j;
        if (grow < N_NODES) {
            float dr = dis[grow];
            float4 o;
            o.x = acc[j][0] * dr;
            o.y = acc[j][1] * dr;
            o.z = acc[j][2] * dr;
            o.w = acc[j][3] * dr;
            *(float4*)&g[(size_t)grow * HID + tx * 4] = o;
        }
    }
}

// hout[i,:] = act( dis[i] * (g[i,:] + sum_{e in [off[i],off[i+1])} g[ssrc[e],:]) + b )
// One wave per row; 4 edge slots x 16 lanes x float4 for 4x memory-level parallelism.
template <bool RELU>
__global__ void k_aggr(const float* __restrict__ g, const int* __restrict__ off,
                       const int* __restrict__ ssrc, const float* __restrict__ dis,
                       const float* __restrict__ bias, float* __restrict__ hout) {
    int row = blockIdx.x * 4 + (threadIdx.x >> 6);
    int lane = threadIdx.x & 63;
    int sub = lane >> 4;   // edge slot 0..3
    int li = lane & 15;    // feature float4 index
    if (row >= N_NODES) return;
    const float4* g4 = (const float4*)g;
    float4 acc = make_float4(0.f, 0.f, 0.f, 0.f);
    int lo = off[row], hi = off[row + 1];
    for (int e = lo + sub; e < hi; e += 4) {
        int s = ssrc[e];
        float4 v = g4[(size_t)s * 16 + li];
        acc.x += v.x; acc.y += v.y; acc.z += v.z; acc.w += v.w;
    }
    // combine the 4 edge slots (lanes differing in bits 4,5 hold same features)
#pragma unroll
    for (int d = 16; d <= 32; d <<= 1) {
        acc.x += __shfl_xor(acc.x, d);
        acc.y += __shfl_xor(acc.y, d);
        acc.z += __shfl_xor(acc.z, d);
        acc.w += __shfl_xor(acc.w, d);
    }
    if (sub == 0) {
        float4 self = g4[(size_t)row * 16 + li];
        float dr = dis[row];
        float4 b = ((const float4*)bias)[li];
        float4 o;
        o.x = dr * (acc.x + self.x) + b.x;
        o.y = dr * (acc.y + self.y) + b.y;
        o.z = dr * (acc.z + self.z) + b.z;
        o.w = dr * (acc.w + self.w) + b.w;
        if (RELU) {
            o.x = fmaxf(o.x, 0.f); o.y = fmaxf(o.y, 0.f);
            o.z = fmaxf(o.z, 0.f); o.w = fmaxf(o.w, 0.f);
        }
        ((float4*)hout)[(size_t)row * 16 + li] = o;
    }
}

// ---------------- pooling + classifier ----------------

__device__ inline int lower_bound_batch(const int* batch, int key) {
    int lo = 0, hi = N_NODES;
    while (lo < hi) {
        int mid = (lo + hi) >> 1;
        if (batch[mid] < key) lo = mid + 1;
        else hi = mid;
    }
    return lo;
}

__global__ void k_pool(const float* __restrict__ h, const int* __restrict__ batch,
                       float* __restrict__ pooled) {
    int gidx = blockIdx.x;  // one block per graph
    int lane = threadIdx.x & 63, w = threadIdx.x >> 6;
    __shared__ float sacc[4][HID];
    int lo = lower_bound_batch(batch, gidx);
    int hi = lower_bound_batch(batch, gidx + 1);
    float acc = 0.f;
    for (int i = lo + w; i < hi; i += 4) acc += h[(size_t)i * HID + lane];
    sacc[w][lane] = acc;
    __syncthreads();
    if (w == 0) {
        float s = sacc[0][lane] + sacc[1][lane] + sacc[2][lane] + sacc[3][lane];
        float cnt = (float)(hi - lo);
        pooled[gidx * HID + lane] = s / fmaxf(cnt, 1.0f);
    }
}

__global__ void k_cls(const float* __restrict__ pooled, const float* __restrict__ Wc1,
                      const float* __restrict__ bc1, const float* __restrict__ Wc2,
                      const float* __restrict__ bc2, float* __restrict__ out) {
    __shared__ float hc[N_GRAPHS][HID / 2];
    int t = threadIdx.x;
    for (int idx = t; idx < N_GRAPHS * (HID / 2); idx += blockDim.x) {
        int gi = idx >> 5, f = idx & 31;
        float a = bc1[f];
#pragma unroll
        for (int k = 0; k < HID; ++k) a = fmaf(pooled[gi * HID + k], Wc1[k * (HID / 2) + f], a);
        hc[gi][f] = fmaxf(a, 0.f);
    }
    __syncthreads();
    for (int idx = t; idx < N_GRAPHS * OUT_DIM; idx += blockDim.x) {
        int gi = idx >> 1, f = idx & 1;
        float a = bc2[f];
#pragma unroll
        for (int k = 0; k < HID / 2; ++k) a = fmaf(hc[gi][k], Wc2[k * OUT_DIM + f], a);
        out[gi * OUT_DIM + f] = a;
    }
}

// ---------------- launch ----------------

extern "C" void kernel_launch(void* const* d_in, const int* in_sizes, int n_in,
                              void* d_out, int out_size, void* d_ws, size_t ws_size,
                              hipStream_t stream) {
    const float* x    = (const float*)d_in[0];
    const int*   eidx = (const int*)d_in[1];   // [2, E] flat: src row then dst row
    const int*   batch= (const int*)d_in[2];
    const float* W1 = (const float*)d_in[3];  const float* b1 = (const float*)d_in[4];
    const float* W2 = (const float*)d_in[5];  const float* b2 = (const float*)d_in[6];
    const float* W3 = (const float*)d_in[7];  const float* b3 = (const float*)d_in[8];
    const float* Wc1 = (const float*)d_in[9];  const float* bc1 = (const float*)d_in[10];
    const float* Wc2 = (const float*)d_in[11]; const float* bc2 = (const float*)d_in[12];
    float* out = (float*)d_out;

    const int* esrc = eidx;
    const int* edst = eidx + N_EDGES;

    size_t o = 0;
    auto alloc = [&](size_t bytes) {
        void* p = (char*)d_ws + o;
        o += (bytes + 255) & ~(size_t)255;
        return p;
    };
    int*   deg_cur = (int*)alloc((size_t)N_NODES * 4);        // deg, later cursor
    int*   off     = (int*)alloc((size_t)(N_NODES + 1) * 4);
    int*   cursor  = (int*)alloc((size_t)(N_NODES + 1) * 4);
    int*   bsums   = (int*)alloc((size_t)SCAN_NB * 4);
    float* dis     = (float*)alloc((size_t)N_NODES * 4);
    int*   ssrc    = (int*)alloc((size_t)N_EDGES * 4);
    float* g       = (float*)alloc((size_t)N_NODES * HID * 4);
    float* hbuf    = (float*)alloc((size_t)N_NODES * HID * 4);
    float* pooled  = (float*)alloc((size_t)N_GRAPHS * HID * 4);
    (void)ws_size;

    const int TB = 256;
    int gridN = (N_NODES + TB - 1) / TB;
    int gridE = (N_EDGES + TB - 1) / TB;
    int gridR = (N_NODES + 3) / 4;           // aggr: 4 rows (waves) per block
    int gridG = (N_NODES + 63) / 64;         // gemm: 64 rows per block

    // 1) degree histogram + dis
    hipMemsetAsync(deg_cur, 0, (size_t)N_NODES * 4, stream);
    k_hist<<<gridE, TB, 0, stream>>>(edst, deg_cur);
    k_dis<<<gridN, TB, 0, stream>>>(deg_cur, dis);

    // 2) exclusive scan deg -> off (and cursor copy)
    k_scan1<<<SCAN_NB, SCAN_BLOCK, 0, stream>>>(deg_cur, off, bsums);
    k_scan2<<<1, 64, 0, stream>>>(bsums, off, cursor);
    k_scan3<<<SCAN_NB, SCAN_BLOCK, 0, stream>>>(off, bsums, cursor);

    // 3) counting-sort edges by dst
    k_scatter<<<gridE, TB, 0, stream>>>(esrc, edst, cursor, ssrc);

    // 4) conv1
    k_gemm<IN_DIM><<<gridG, TB, 0, stream>>>(x, W1, dis, g);
    k_aggr<true><<<gridR, TB, 0, stream>>>(g, off, ssrc, dis, b1, hbuf);

    // 5) conv2
    k_gemm<HID><<<gridG, TB, 0, stream>>>(hbuf, W2, dis, g);
    k_aggr<true><<<gridR, TB, 0, stream>>>(g, off, ssrc, dis, b2, hbuf);

    // 6) conv3 (no relu)
    k_gemm<HID><<<gridG, TB, 0, stream>>>(hbuf, W3, dis, g);
    k_aggr<false><<<gridR, TB, 0, stream>>>(g, off, ssrc, dis, b3, hbuf);

    // 7) pool + classifier
    k_pool<<<N_GRAPHS, TB, 0, stream>>>(hbuf, batch, pooled);
    k_cls<<<1, TB, 0, stream>>>(pooled, Wc1, bc1, Wc2, bc2, out);
}